// Round 1
// baseline (805.623 us; speedup 1.0000x reference)
//
#include <hip/hip_runtime.h>

static constexpr int   kBatch   = 2097152;
static constexpr int   H        = 32;
static constexpr float kActScale = 1.0f / 12.0f;
static constexpr float kAct2     = 1.0f / 6.0f;   // 2*ACT_SCALE

// Device-global table:
// [0,1024)    spA0        (softplus(raw_A_0), row-major [i][j])
// [1024,2048) spA1
// [2048,3072) spA0T       (transposed copy for backward)
// [3072,4096) spA1T
// [4096,4128) spAout      (softplus(raw_A_out))
// [4128]      cref        (dW/dI1 at z0 = 0)
__device__ float g_tab[4136];

__device__ __forceinline__ float rcp_f(float x) { return __fdividef(1.0f, x); }

__device__ __forceinline__ float sp_only(float x) {
    float e = __expf(-fabsf(x));
    return fmaxf(x, 0.0f) + __logf(1.0f + e);
}
__device__ __forceinline__ float sig_only(float x) {
    float e = __expf(-fabsf(x));
    float r = rcp_f(1.0f + e);
    return (x >= 0.0f) ? r : e * r;
}
// softplus(x), and sigmoid(x) via out-param. Stable for |x| up to hundreds.
__device__ __forceinline__ float sp_sig(float x, float& sig) {
    float e  = __expf(-fabsf(x));   // in (0,1]
    float oe = 1.0f + e;
    float r  = rcp_f(oe);
    sig = (x >= 0.0f) ? r : e * r;
    return fmaxf(x, 0.0f) + __logf(oe);
}

// ---------------- prep: softplus tables + reference-gradient constant --------
__global__ __launch_bounds__(256) void icnn_prep(
    const float* __restrict__ rawA0, const float* __restrict__ rawA1,
    const float* __restrict__ rawAout,
    const float* __restrict__ W1,  const float* __restrict__ b1,
    const float* __restrict__ Wc0, const float* __restrict__ bc0,
    const float* __restrict__ Wc1, const float* __restrict__ bc1,
    const float* __restrict__ wout)
{
    __shared__ float sA0[1024], sA1[1024], sAout[32];
    const int t = threadIdx.x;
    for (int k = t; k < 1024; k += 256) { float v = sp_only(rawA0[k]); sA0[k] = v; g_tab[k] = v; }
    for (int k = t; k < 1024; k += 256) { float v = sp_only(rawA1[k]); sA1[k] = v; g_tab[1024 + k] = v; }
    if (t < 32) { float v = sp_only(rawAout[t]); sAout[t] = v; g_tab[4096 + t] = v; }
    __syncthreads();
    // transposed copies (contiguous scalar loads in the backward matvecs)
    for (int k = t; k < 1024; k += 256) g_tab[2048 + k] = sA0[(k & 31) * 32 + (k >> 5)];
    for (int k = t; k < 1024; k += 256) g_tab[3072 + k] = sA1[(k & 31) * 32 + (k >> 5)];

    // reference gradient dW/dI1 at z0 = (0,0), computed by wave-0 lanes 0..31
    if (t < 32) {
        const int i = t;
        float sa, sc0v;
        float zi = sp_sig(b1[i], sa);
        // layer 0
        float u = 0.0f;
        for (int j = 0; j < 32; j++) u = fmaf(sA0[i * 32 + j], __shfl(zi, j, 64), u);
        float su; float t0 = sp_sig(u, su);
        float d0 = kAct2 * t0 * su;
        float spc = sp_sig(bc0[i], sc0v);
        float zn = fmaf(kActScale * t0, t0, spc);
        // layer 1
        float u1 = 0.0f;
        for (int j = 0; j < 32; j++) u1 = fmaf(sA1[i * 32 + j], __shfl(zn, j, 64), u1);
        float su1; float t1 = sp_sig(u1, su1);
        float d1 = sAout[i] * kAct2 * t1 * su1;
        float contrib = Wc1[2 * i] * sAout[i] * sig_only(bc1[i]);
        // backward
        float g = 0.0f;
        for (int j = 0; j < 32; j++) g = fmaf(sA1[j * 32 + i], __shfl(d1, j, 64), g);
        contrib = fmaf(Wc0[2 * i], g * sc0v, contrib);
        float gu0 = g * d0;
        float ga = 0.0f;
        for (int j = 0; j < 32; j++) ga = fmaf(sA0[j * 32 + i], __shfl(gu0, j, 64), ga);
        ga *= sa;
        contrib = fmaf(W1[2 * i], ga, contrib);
        // reduce across the 32 lanes
        for (int off = 16; off >= 1; off >>= 1)
            contrib += __shfl_down(contrib, off, 32);
        if (i == 0) g_tab[4128] = wout[0] + contrib;
    }
}

// ---------------- main: one thread per row, fused fwd+bwd --------------------
__global__ __launch_bounds__(256) void icnn_main(
    const float* __restrict__ eps,
    const float* __restrict__ W1,  const float* __restrict__ b1,
    const float* __restrict__ Wc0, const float* __restrict__ bc0,
    const float* __restrict__ Wc1, const float* __restrict__ bc1,
    const float* __restrict__ wout,
    float* __restrict__ out)
{
    const int row = blockIdx.x * 256 + threadIdx.x;
    if (row >= kBatch) return;

    const float e11 = eps[row * 3 + 0];
    const float e22 = eps[row * 3 + 1];
    const float e12 = eps[row * 3 + 2];
    const float x1 = e11 + e22;
    const float x2 = e11 * e11 + 2.0f * e12 * e12 + e22 * e22;

    const float* __restrict__ A0   = g_tab;
    const float* __restrict__ A1   = g_tab + 1024;
    const float* __restrict__ A0T  = g_tab + 2048;
    const float* __restrict__ A1T  = g_tab + 3072;
    const float* __restrict__ aout = g_tab + 4096;

    float sa[H], d0[H], sc0[H], d1[H];

    // first layer: z = softplus(W1 z0 + b1), save sigmoid
    float z[H];
    #pragma unroll
    for (int i = 0; i < H; i++) {
        float a = fmaf(W1[2 * i], x1, fmaf(W1[2 * i + 1], x2, b1[i]));
        z[i] = sp_sig(a, sa[i]);
    }

    // layer 0: u0 = A0 z ; z' = ACT*sp(u0)^2 + sp(c0)
    float zn[H];
    #pragma unroll
    for (int i = 0; i < H; i++) {
        float u = 0.0f;
        #pragma unroll
        for (int j = 0; j < H; j++) u = fmaf(A0[i * H + j], z[j], u);
        float su; float t = sp_sig(u, su);
        d0[i] = kAct2 * t * su;
        float c = fmaf(Wc0[2 * i], x1, fmaf(Wc0[2 * i + 1], x2, bc0[i]));
        float sc; float spc = sp_sig(c, sc);
        sc0[i] = sc;
        zn[i] = fmaf(kActScale * t, t, spc);
    }

    // layer 1: only d1 = aout .* dz2/du1 is needed; fold the c1-skip gradient
    // immediately (g_{z2} = aout is constant).
    float g0 = wout[0], gq = wout[1];
    #pragma unroll
    for (int i = 0; i < H; i++) {
        float u = 0.0f;
        #pragma unroll
        for (int j = 0; j < H; j++) u = fmaf(A1[i * H + j], zn[j], u);
        float su; float t = sp_sig(u, su);
        d1[i] = aout[i] * kAct2 * t * su;
        float c = fmaf(Wc1[2 * i], x1, fmaf(Wc1[2 * i + 1], x2, bc1[i]));
        float w = aout[i] * sig_only(c);
        g0 = fmaf(Wc1[2 * i], w, g0);
        gq = fmaf(Wc1[2 * i + 1], w, gq);
    }

    // backward: g1 = A1^T d1
    float g[H];
    #pragma unroll
    for (int i = 0; i < H; i++) {
        float acc = 0.0f;
        #pragma unroll
        for (int j = 0; j < H; j++) acc = fmaf(A1T[i * H + j], d1[j], acc);
        g[i] = acc;
    }
    // layer-0 skip gradient + gate by d0
    #pragma unroll
    for (int i = 0; i < H; i++) {
        float w = g[i] * sc0[i];
        g0 = fmaf(Wc0[2 * i], w, g0);
        gq = fmaf(Wc0[2 * i + 1], w, gq);
        g[i] *= d0[i];
    }
    // through A0 and the first layer
    #pragma unroll
    for (int i = 0; i < H; i++) {
        float acc = 0.0f;
        #pragma unroll
        for (int j = 0; j < H; j++) acc = fmaf(A0T[i * H + j], g[j], acc);
        float ga = acc * sa[i];
        g0 = fmaf(W1[2 * i], ga, g0);
        gq = fmaf(W1[2 * i + 1], ga, gq);
    }

    const float cref = g_tab[4128];
    const float dI1 = g0 - cref;
    const float dI2 = gq;
    out[row * 3 + 0] = fmaf(2.0f * e11, dI2, dI1);
    out[row * 3 + 1] = fmaf(2.0f * e22, dI2, dI1);
    out[row * 3 + 2] = 2.0f * e12 * dI2;
}

extern "C" void kernel_launch(void* const* d_in, const int* in_sizes, int n_in,
                              void* d_out, int out_size, void* d_ws, size_t ws_size,
                              hipStream_t stream)
{
    (void)in_sizes; (void)n_in; (void)out_size; (void)d_ws; (void)ws_size;
    const float* eps    = (const float*)d_in[0];
    const float* W1     = (const float*)d_in[1];
    const float* b1     = (const float*)d_in[2];
    const float* rawA0  = (const float*)d_in[3];
    const float* rawA1  = (const float*)d_in[4];
    const float* Wc0    = (const float*)d_in[5];
    const float* bc0    = (const float*)d_in[6];
    const float* Wc1    = (const float*)d_in[7];
    const float* bc1    = (const float*)d_in[8];
    const float* rawAout= (const float*)d_in[9];
    const float* wout   = (const float*)d_in[10];
    float* out = (float*)d_out;

    icnn_prep<<<1, 256, 0, stream>>>(rawA0, rawA1, rawAout, W1, b1, Wc0, bc0, Wc1, bc1, wout);
    icnn_main<<<kBatch / 256, 256, 0, stream>>>(eps, W1, b1, Wc0, bc0, Wc1, bc1, wout, out);
}

// Round 2
// 517.147 us; speedup vs baseline: 1.5578x; 1.5578x over previous
//
#include <hip/hip_runtime.h>

static constexpr int   kBatch   = 2097152;
static constexpr int   H        = 32;
static constexpr float kActScale = 1.0f / 12.0f;
static constexpr float kAct2     = 1.0f / 6.0f;   // 2*ACT_SCALE

// Device-global table:
// [0,1024)    spA0        (softplus(raw_A_0), row-major [i][j])
// [1024,2048) spA1
// [2048,3072) spA0T       (transposed copy for backward)
// [3072,4096) spA1T
// [4096,4128) spAout      (softplus(raw_A_out))
// [4128]      cref        (dW/dI1 at z0 = 0)
__device__ float g_tab[4136];

__device__ __forceinline__ float rcp_f(float x) { return __fdividef(1.0f, x); }

__device__ __forceinline__ float sp_only(float x) {
    float e = __expf(-fabsf(x));
    return fmaxf(x, 0.0f) + __logf(1.0f + e);
}
__device__ __forceinline__ float sig_only(float x) {
    float e = __expf(-fabsf(x));
    float r = rcp_f(1.0f + e);
    return (x >= 0.0f) ? r : e * r;
}
// softplus(x), and sigmoid(x) via out-param. Stable for |x| up to hundreds.
__device__ __forceinline__ float sp_sig(float x, float& sig) {
    float e  = __expf(-fabsf(x));   // in (0,1]
    float oe = 1.0f + e;
    float r  = rcp_f(oe);
    sig = (x >= 0.0f) ? r : e * r;
    return fmaxf(x, 0.0f) + __logf(oe);
}

// ---------------- prep: softplus tables + reference-gradient constant --------
__global__ __launch_bounds__(256) void icnn_prep(
    const float* __restrict__ rawA0, const float* __restrict__ rawA1,
    const float* __restrict__ rawAout,
    const float* __restrict__ W1,  const float* __restrict__ b1,
    const float* __restrict__ Wc0, const float* __restrict__ bc0,
    const float* __restrict__ Wc1, const float* __restrict__ bc1,
    const float* __restrict__ wout)
{
    __shared__ float sA0[1024], sA1[1024], sAout[32];
    const int t = threadIdx.x;
    for (int k = t; k < 1024; k += 256) { float v = sp_only(rawA0[k]); sA0[k] = v; g_tab[k] = v; }
    for (int k = t; k < 1024; k += 256) { float v = sp_only(rawA1[k]); sA1[k] = v; g_tab[1024 + k] = v; }
    if (t < 32) { float v = sp_only(rawAout[t]); sAout[t] = v; g_tab[4096 + t] = v; }
    __syncthreads();
    // transposed copies (contiguous scalar loads in the backward matvecs)
    for (int k = t; k < 1024; k += 256) g_tab[2048 + k] = sA0[(k & 31) * 32 + (k >> 5)];
    for (int k = t; k < 1024; k += 256) g_tab[3072 + k] = sA1[(k & 31) * 32 + (k >> 5)];

    // reference gradient dW/dI1 at z0 = (0,0), computed by wave-0 lanes 0..31
    if (t < 32) {
        const int i = t;
        float sa, sc0v;
        float zi = sp_sig(b1[i], sa);
        // layer 0
        float u = 0.0f;
        for (int j = 0; j < 32; j++) u = fmaf(sA0[i * 32 + j], __shfl(zi, j, 64), u);
        float su; float t0 = sp_sig(u, su);
        float d0 = kAct2 * t0 * su;
        float spc = sp_sig(bc0[i], sc0v);
        float zn = fmaf(kActScale * t0, t0, spc);
        // layer 1
        float u1 = 0.0f;
        for (int j = 0; j < 32; j++) u1 = fmaf(sA1[i * 32 + j], __shfl(zn, j, 64), u1);
        float su1; float t1 = sp_sig(u1, su1);
        float d1 = sAout[i] * kAct2 * t1 * su1;
        float contrib = Wc1[2 * i] * sAout[i] * sig_only(bc1[i]);
        // backward
        float g = 0.0f;
        for (int j = 0; j < 32; j++) g = fmaf(sA1[j * 32 + i], __shfl(d1, j, 64), g);
        contrib = fmaf(Wc0[2 * i], g * sc0v, contrib);
        float gu0 = g * d0;
        float ga = 0.0f;
        for (int j = 0; j < 32; j++) ga = fmaf(sA0[j * 32 + i], __shfl(gu0, j, 64), ga);
        ga *= sa;
        contrib = fmaf(W1[2 * i], ga, contrib);
        // reduce across the 32 lanes
        for (int off = 16; off >= 1; off >>= 1)
            contrib += __shfl_down(contrib, off, 32);
        if (i == 0) g_tab[4128] = wout[0] + contrib;
    }
}

// ---------------- main: one thread per row, fused fwd+bwd --------------------
// Spill-free restructure: peak live state is {d0, zn, d1-partial} or
// {d0, d1, g-partial} = 96 floats + ~15 temps. sigmoid(a_i) and sigmoid(c0_i)
// are RECOMPUTED in the backward pass (2 FMA + exp + rcp each) instead of
// stored -- cheaper than a spill. __launch_bounds__(256,4): 128-VGPR budget,
// 4 waves/SIMD.
__global__ __launch_bounds__(256, 4) void icnn_main(
    const float* __restrict__ eps,
    const float* __restrict__ W1,  const float* __restrict__ b1,
    const float* __restrict__ Wc0, const float* __restrict__ bc0,
    const float* __restrict__ Wc1, const float* __restrict__ bc1,
    const float* __restrict__ wout,
    float* __restrict__ out)
{
    const int row = blockIdx.x * 256 + threadIdx.x;
    if (row >= kBatch) return;

    const float e11 = eps[row * 3 + 0];
    const float e22 = eps[row * 3 + 1];
    const float e12 = eps[row * 3 + 2];
    const float x1 = e11 + e22;
    const float x2 = e11 * e11 + 2.0f * e12 * e12 + e22 * e22;

    const float* __restrict__ A0   = g_tab;
    const float* __restrict__ A1   = g_tab + 1024;
    const float* __restrict__ A0T  = g_tab + 2048;
    const float* __restrict__ A1T  = g_tab + 3072;
    const float* __restrict__ aout = g_tab + 4096;

    float g0 = wout[0], gq = wout[1];

    // ---- L1 forward: z = softplus(W1 z0 + b1). sigmoid recomputed later.
    float z[H];
    #pragma unroll
    for (int i = 0; i < H; i++) {
        float a = fmaf(W1[2 * i], x1, fmaf(W1[2 * i + 1], x2, b1[i]));
        z[i] = sp_only(a);
    }

    // ---- layer 0: u = A0 z; zn = ACT*sp(u)^2 + sp(c0); d0 = dz/du.
    // sigmoid(c0) recomputed later.  [live: z -> d0, zn]
    float zn[H], d0[H];
    #pragma unroll
    for (int i = 0; i < H; i++) {
        float u = 0.0f;
        #pragma unroll
        for (int j = 0; j < H; j++) u = fmaf(A0[i * H + j], z[j], u);
        float su; float t = sp_sig(u, su);
        d0[i] = kAct2 * t * su;
        float c = fmaf(Wc0[2 * i], x1, fmaf(Wc0[2 * i + 1], x2, bc0[i]));
        zn[i] = fmaf(kActScale * t, t, sp_only(c));
    }

    // ---- layer 1: d1 = aout .* dz2/du1; fold the c1-skip gradient now
    // (g_{z2} = aout is a constant vector).  [live: d0, zn -> d0, d1]
    float d1[H];
    #pragma unroll
    for (int i = 0; i < H; i++) {
        float u = 0.0f;
        #pragma unroll
        for (int j = 0; j < H; j++) u = fmaf(A1[i * H + j], zn[j], u);
        float su; float t = sp_sig(u, su);
        d1[i] = aout[i] * kAct2 * t * su;
        float c = fmaf(Wc1[2 * i], x1, fmaf(Wc1[2 * i + 1], x2, bc1[i]));
        float w = aout[i] * sig_only(c);
        g0 = fmaf(Wc1[2 * i], w, g0);
        gq = fmaf(Wc1[2 * i + 1], w, gq);
    }

    // ---- backward: g = A1^T d1.  [live: d0, d1 -> d0, g]
    float g[H];
    #pragma unroll
    for (int i = 0; i < H; i++) {
        float acc = 0.0f;
        #pragma unroll
        for (int j = 0; j < H; j++) acc = fmaf(A1T[i * H + j], d1[j], acc);
        g[i] = acc;
    }

    // ---- layer-0 skip gradient (recompute sigmoid(c0)), gate by d0.
    #pragma unroll
    for (int i = 0; i < H; i++) {
        float c = fmaf(Wc0[2 * i], x1, fmaf(Wc0[2 * i + 1], x2, bc0[i]));
        float w = g[i] * sig_only(c);
        g0 = fmaf(Wc0[2 * i], w, g0);
        gq = fmaf(Wc0[2 * i + 1], w, gq);
        g[i] *= d0[i];
    }

    // ---- through A0^T and the first layer (recompute sigmoid(a)).
    #pragma unroll
    for (int i = 0; i < H; i++) {
        float acc = 0.0f;
        #pragma unroll
        for (int j = 0; j < H; j++) acc = fmaf(A0T[i * H + j], g[j], acc);
        float a = fmaf(W1[2 * i], x1, fmaf(W1[2 * i + 1], x2, b1[i]));
        float ga = acc * sig_only(a);
        g0 = fmaf(W1[2 * i], ga, g0);
        gq = fmaf(W1[2 * i + 1], ga, gq);
    }

    const float cref = g_tab[4128];
    const float dI1 = g0 - cref;
    const float dI2 = gq;
    out[row * 3 + 0] = fmaf(2.0f * e11, dI2, dI1);
    out[row * 3 + 1] = fmaf(2.0f * e22, dI2, dI1);
    out[row * 3 + 2] = 2.0f * e12 * dI2;
}

extern "C" void kernel_launch(void* const* d_in, const int* in_sizes, int n_in,
                              void* d_out, int out_size, void* d_ws, size_t ws_size,
                              hipStream_t stream)
{
    (void)in_sizes; (void)n_in; (void)out_size; (void)d_ws; (void)ws_size;
    const float* eps    = (const float*)d_in[0];
    const float* W1     = (const float*)d_in[1];
    const float* b1     = (const float*)d_in[2];
    const float* rawA0  = (const float*)d_in[3];
    const float* rawA1  = (const float*)d_in[4];
    const float* Wc0    = (const float*)d_in[5];
    const float* bc0    = (const float*)d_in[6];
    const float* Wc1    = (const float*)d_in[7];
    const float* bc1    = (const float*)d_in[8];
    const float* rawAout= (const float*)d_in[9];
    const float* wout   = (const float*)d_in[10];
    float* out = (float*)d_out;

    icnn_prep<<<1, 256, 0, stream>>>(rawA0, rawA1, rawAout, W1, b1, Wc0, bc0, Wc1, bc1, wout);
    icnn_main<<<kBatch / 256, 256, 0, stream>>>(eps, W1, b1, Wc0, bc0, Wc1, bc1, wout, out);
}

// Round 3
// 514.625 us; speedup vs baseline: 1.5655x; 1.0049x over previous
//
#include <hip/hip_runtime.h>

static constexpr int   kBatch   = 2097152;
static constexpr int   H        = 32;
static constexpr float kActScale = 1.0f / 12.0f;
static constexpr float kAct2     = 1.0f / 6.0f;   // 2*ACT_SCALE

// Device-global table:
// [0,1024)    spA0        (softplus(raw_A_0), row-major [i][j])
// [1024,2048) spA1
// [2048,3072) spA0T       (transposed copy for backward)
// [3072,4096) spA1T
// [4096,4128) spAout      (softplus(raw_A_out))
// [4128]      cref        (dW/dI1 at z0 = 0)
__device__ float g_tab[4136];

__device__ __forceinline__ float rcp_f(float x) { return __fdividef(1.0f, x); }

__device__ __forceinline__ float sp_only(float x) {
    float e = __expf(-fabsf(x));
    return fmaxf(x, 0.0f) + __logf(1.0f + e);
}
__device__ __forceinline__ float sig_only(float x) {
    float e = __expf(-fabsf(x));
    float r = rcp_f(1.0f + e);
    return (x >= 0.0f) ? r : e * r;
}
// softplus(x), and sigmoid(x) via out-param. Stable for |x| up to hundreds.
__device__ __forceinline__ float sp_sig(float x, float& sig) {
    float e  = __expf(-fabsf(x));   // in (0,1]
    float oe = 1.0f + e;
    float r  = rcp_f(oe);
    sig = (x >= 0.0f) ? r : e * r;
    return fmaxf(x, 0.0f) + __logf(oe);
}

// ---------------- prep: softplus tables + reference-gradient constant --------
__global__ __launch_bounds__(256) void icnn_prep(
    const float* __restrict__ rawA0, const float* __restrict__ rawA1,
    const float* __restrict__ rawAout,
    const float* __restrict__ W1,  const float* __restrict__ b1,
    const float* __restrict__ Wc0, const float* __restrict__ bc0,
    const float* __restrict__ Wc1, const float* __restrict__ bc1,
    const float* __restrict__ wout)
{
    __shared__ float sA0[1024], sA1[1024], sAout[32];
    const int t = threadIdx.x;
    for (int k = t; k < 1024; k += 256) { float v = sp_only(rawA0[k]); sA0[k] = v; g_tab[k] = v; }
    for (int k = t; k < 1024; k += 256) { float v = sp_only(rawA1[k]); sA1[k] = v; g_tab[1024 + k] = v; }
    if (t < 32) { float v = sp_only(rawAout[t]); sAout[t] = v; g_tab[4096 + t] = v; }
    __syncthreads();
    // transposed copies (contiguous scalar loads in the backward matvecs)
    for (int k = t; k < 1024; k += 256) g_tab[2048 + k] = sA0[(k & 31) * 32 + (k >> 5)];
    for (int k = t; k < 1024; k += 256) g_tab[3072 + k] = sA1[(k & 31) * 32 + (k >> 5)];

    // reference gradient dW/dI1 at z0 = (0,0), computed by wave-0 lanes 0..31
    if (t < 32) {
        const int i = t;
        float sa, sc0v;
        float zi = sp_sig(b1[i], sa);
        // layer 0
        float u = 0.0f;
        for (int j = 0; j < 32; j++) u = fmaf(sA0[i * 32 + j], __shfl(zi, j, 64), u);
        float su; float t0 = sp_sig(u, su);
        float d0 = kAct2 * t0 * su;
        float spc = sp_sig(bc0[i], sc0v);
        float zn = fmaf(kActScale * t0, t0, spc);
        // layer 1
        float u1 = 0.0f;
        for (int j = 0; j < 32; j++) u1 = fmaf(sA1[i * 32 + j], __shfl(zn, j, 64), u1);
        float su1; float t1 = sp_sig(u1, su1);
        float d1 = sAout[i] * kAct2 * t1 * su1;
        float contrib = Wc1[2 * i] * sAout[i] * sig_only(bc1[i]);
        // backward
        float g = 0.0f;
        for (int j = 0; j < 32; j++) g = fmaf(sA1[j * 32 + i], __shfl(d1, j, 64), g);
        contrib = fmaf(Wc0[2 * i], g * sc0v, contrib);
        float gu0 = g * d0;
        float ga = 0.0f;
        for (int j = 0; j < 32; j++) ga = fmaf(sA0[j * 32 + i], __shfl(gu0, j, 64), ga);
        ga *= sa;
        contrib = fmaf(W1[2 * i], ga, contrib);
        // reduce across the 32 lanes
        for (int off = 16; off >= 1; off >>= 1)
            contrib += __shfl_down(contrib, off, 32);
        if (i == 0) g_tab[4128] = wout[0] + contrib;
    }
}

// ---------------- main: one thread per row, fused fwd+bwd --------------------
// Peak live state ~96 floats + temps. __launch_bounds__(256,3) -> 168-VGPR
// budget: fits without spilling (R2's (256,4)=128 cap forced spill/remat,
// 3x instruction bloat at VGPR_Count=60). 3 waves/SIMD is plenty for a
// VALU-bound kernel with 32 independent FMA chains per matvec.
__global__ __launch_bounds__(256, 3) void icnn_main(
    const float* __restrict__ eps,
    const float* __restrict__ W1,  const float* __restrict__ b1,
    const float* __restrict__ Wc0, const float* __restrict__ bc0,
    const float* __restrict__ Wc1, const float* __restrict__ bc1,
    const float* __restrict__ wout,
    float* __restrict__ out)
{
    const int row = blockIdx.x * 256 + threadIdx.x;
    if (row >= kBatch) return;

    const float e11 = eps[row * 3 + 0];
    const float e22 = eps[row * 3 + 1];
    const float e12 = eps[row * 3 + 2];
    const float x1 = e11 + e22;
    const float x2 = e11 * e11 + 2.0f * e12 * e12 + e22 * e22;

    const float* __restrict__ A0   = g_tab;
    const float* __restrict__ A1   = g_tab + 1024;
    const float* __restrict__ A0T  = g_tab + 2048;
    const float* __restrict__ A1T  = g_tab + 3072;
    const float* __restrict__ aout = g_tab + 4096;

    float g0 = wout[0], gq = wout[1];

    // ---- L1 forward: z = softplus(W1 z0 + b1). sigmoid recomputed later.
    float z[H];
    #pragma unroll
    for (int i = 0; i < H; i++) {
        float a = fmaf(W1[2 * i], x1, fmaf(W1[2 * i + 1], x2, b1[i]));
        z[i] = sp_only(a);
    }

    // ---- layer 0: u = A0 z; zn = ACT*sp(u)^2 + sp(c0); d0 = dz/du.
    // sigmoid(c0) recomputed later.  [live: z -> d0, zn; peak 96]
    float zn[H], d0[H];
    #pragma unroll
    for (int i = 0; i < H; i++) {
        float u = 0.0f;
        #pragma unroll
        for (int j = 0; j < H; j++) u = fmaf(A0[i * H + j], z[j], u);
        float su; float t = sp_sig(u, su);
        d0[i] = kAct2 * t * su;
        float c = fmaf(Wc0[2 * i], x1, fmaf(Wc0[2 * i + 1], x2, bc0[i]));
        zn[i] = fmaf(kActScale * t, t, sp_only(c));
    }

    // ---- layer 1: d1 = aout .* dz2/du1; fold the c1-skip gradient now
    // (g_{z2} = aout is a constant vector).  [live: d0, zn -> d0, d1; peak 96]
    float d1[H];
    #pragma unroll
    for (int i = 0; i < H; i++) {
        float u = 0.0f;
        #pragma unroll
        for (int j = 0; j < H; j++) u = fmaf(A1[i * H + j], zn[j], u);
        float su; float t = sp_sig(u, su);
        d1[i] = aout[i] * kAct2 * t * su;
        float c = fmaf(Wc1[2 * i], x1, fmaf(Wc1[2 * i + 1], x2, bc1[i]));
        float w = aout[i] * sig_only(c);
        g0 = fmaf(Wc1[2 * i], w, g0);
        gq = fmaf(Wc1[2 * i + 1], w, gq);
    }

    // ---- backward: acc = (A1^T d1)_i; fold layer-0 skip gradient (recompute
    // sigmoid(c0)) immediately; gate by d0.  [live: d0, d1 -> g; peak 96]
    float g[H];
    #pragma unroll
    for (int i = 0; i < H; i++) {
        float acc = 0.0f;
        #pragma unroll
        for (int j = 0; j < H; j++) acc = fmaf(A1T[i * H + j], d1[j], acc);
        float c = fmaf(Wc0[2 * i], x1, fmaf(Wc0[2 * i + 1], x2, bc0[i]));
        float w = acc * sig_only(c);
        g0 = fmaf(Wc0[2 * i], w, g0);
        gq = fmaf(Wc0[2 * i + 1], w, gq);
        g[i] = acc * d0[i];
    }

    // ---- through A0^T and the first layer (recompute sigmoid(a)).
    #pragma unroll
    for (int i = 0; i < H; i++) {
        float acc = 0.0f;
        #pragma unroll
        for (int j = 0; j < H; j++) acc = fmaf(A0T[i * H + j], g[j], acc);
        float a = fmaf(W1[2 * i], x1, fmaf(W1[2 * i + 1], x2, b1[i]));
        float ga = acc * sig_only(a);
        g0 = fmaf(W1[2 * i], ga, g0);
        gq = fmaf(W1[2 * i + 1], ga, gq);
    }

    const float cref = g_tab[4128];
    const float dI1 = g0 - cref;
    const float dI2 = gq;
    out[row * 3 + 0] = fmaf(2.0f * e11, dI2, dI1);
    out[row * 3 + 1] = fmaf(2.0f * e22, dI2, dI1);
    out[row * 3 + 2] = 2.0f * e12 * dI2;
}

extern "C" void kernel_launch(void* const* d_in, const int* in_sizes, int n_in,
                              void* d_out, int out_size, void* d_ws, size_t ws_size,
                              hipStream_t stream)
{
    (void)in_sizes; (void)n_in; (void)out_size; (void)d_ws; (void)ws_size;
    const float* eps    = (const float*)d_in[0];
    const float* W1     = (const float*)d_in[1];
    const float* b1     = (const float*)d_in[2];
    const float* rawA0  = (const float*)d_in[3];
    const float* rawA1  = (const float*)d_in[4];
    const float* Wc0    = (const float*)d_in[5];
    const float* bc0    = (const float*)d_in[6];
    const float* Wc1    = (const float*)d_in[7];
    const float* bc1    = (const float*)d_in[8];
    const float* rawAout= (const float*)d_in[9];
    const float* wout   = (const float*)d_in[10];
    float* out = (float*)d_out;

    icnn_prep<<<1, 256, 0, stream>>>(rawA0, rawA1, rawAout, W1, b1, Wc0, bc0, Wc1, bc1, wout);
    icnn_main<<<kBatch / 256, 256, 0, stream>>>(eps, W1, b1, Wc0, bc0, Wc1, bc1, wout, out);
}